// Round 7
// baseline (374.636 us; speedup 1.0000x reference)
//
#include <hip/hip_runtime.h>

#define T_SEQ 512
#define B_BAT 256
#define ED_ 100
#define NVOC 32000
#define DT_C 1e-3f
#define SC_C 0.2f
#define MU_C 1.0f
#define NSTEP 20
#define CCH 8                 // tokens per pipeline chunk
#define NCH (T_SEQ / CCH)     // 64 chunks
#define NIT (NCH + 6)         // pipeline depth 7 stages

typedef float v2f __attribute__((ext_vector_type(2)));

// ---------------------------------------------------------------------------
// K0: tab[v][c] = relu(E[v] @ W1cat + b1cat), c interleaved (2u+p) for the
// per-token v2f gather in W0. 250 blocks.
// ---------------------------------------------------------------------------
__global__ __launch_bounds__(256) void k0_table(
    const float* __restrict__ E,
    const float* __restrict__ W1r, const float* __restrict__ b1r,
    const float* __restrict__ W1i, const float* __restrict__ b1i,
    float* __restrict__ tab)
{
    __shared__ float embT[128 * 104];
    __shared__ float Wc[100 * 128];
    __shared__ float bias[128];
    const int tid = threadIdx.x;
    const int row0g = blockIdx.x * 128;

    for (int idx = tid; idx < 100 * 128; idx += 256) {
        int k = idx >> 7, c = idx & 127;
        Wc[idx] = (c & 1) ? W1i[k * 64 + (c >> 1)] : W1r[k * 64 + (c >> 1)];
    }
    if (tid < 128) bias[tid] = (tid & 1) ? b1i[tid >> 1] : b1r[tid >> 1];
    {
        int r = tid >> 1, half = tid & 1;
        const float4* src = (const float4*)(E + (size_t)(row0g + r) * ED_);
        float4* dst = (float4*)&embT[r * 104];
        for (int j = half; j < 25; j += 2) dst[j] = src[j];
    }
    __syncthreads();

    const int col0 = (tid & 15) * 8;
    const int row0 = (tid >> 4) * 8;
    float acc[8][8];
#pragma unroll
    for (int i = 0; i < 8; ++i)
#pragma unroll
        for (int j = 0; j < 8; ++j) acc[i][j] = 0.f;

    for (int k0 = 0; k0 < 100; k0 += 4) {
        float ev[8][4];
#pragma unroll
        for (int i = 0; i < 8; ++i)
            *(float4*)ev[i] = *(const float4*)&embT[(row0 + i) * 104 + k0];
#pragma unroll
        for (int kk = 0; kk < 4; ++kk) {
            float4 wA = *(const float4*)&Wc[(k0 + kk) * 128 + col0];
            float4 wB = *(const float4*)&Wc[(k0 + kk) * 128 + col0 + 4];
#pragma unroll
            for (int i = 0; i < 8; ++i) {
                float e = ev[i][kk];
                acc[i][0] = fmaf(e, wA.x, acc[i][0]);
                acc[i][1] = fmaf(e, wA.y, acc[i][1]);
                acc[i][2] = fmaf(e, wA.z, acc[i][2]);
                acc[i][3] = fmaf(e, wA.w, acc[i][3]);
                acc[i][4] = fmaf(e, wB.x, acc[i][4]);
                acc[i][5] = fmaf(e, wB.y, acc[i][5]);
                acc[i][6] = fmaf(e, wB.z, acc[i][6]);
                acc[i][7] = fmaf(e, wB.w, acc[i][7]);
            }
        }
    }
#pragma unroll
    for (int i = 0; i < 8; ++i) {
        float4 o0, o1;
        o0.x = fmaxf(acc[i][0] + bias[col0 + 0], 0.f);
        o0.y = fmaxf(acc[i][1] + bias[col0 + 1], 0.f);
        o0.z = fmaxf(acc[i][2] + bias[col0 + 2], 0.f);
        o0.w = fmaxf(acc[i][3] + bias[col0 + 3], 0.f);
        o1.x = fmaxf(acc[i][4] + bias[col0 + 4], 0.f);
        o1.y = fmaxf(acc[i][5] + bias[col0 + 5], 0.f);
        o1.z = fmaxf(acc[i][6] + bias[col0 + 6], 0.f);
        o1.w = fmaxf(acc[i][7] + bias[col0 + 7], 0.f);
        size_t base = (size_t)(row0g + row0 + i) * 128 + col0;
        *(float4*)&tab[base] = o0;
        *(float4*)&tab[base + 4] = o1;
    }
}

// ---------------------------------------------------------------------------
// Fused pipeline, one block per batch element, 8 waves, 7-stage chunk
// pipeline, planar LDS rings. This round: code-size diet — rolled loops
// everywhere (forcing staged via W0-private LDS fbuf so no register arrays),
// small unroll factors. Hot code ~5 KB (was ~50 KB) to stop I$ thrash.
// ---------------------------------------------------------------------------
__global__ __launch_bounds__(512, 1) void donn_pipe(
    const float* __restrict__ tab, const int* __restrict__ xin,
    const float* __restrict__ om1, const float* __restrict__ om2,
    const float* __restrict__ Wp1, const float* __restrict__ bp1,
    const float* __restrict__ W2r, const float* __restrict__ b2r,
    const float* __restrict__ W2i, const float* __restrict__ b2i,
    const float* __restrict__ Wp2, const float* __restrict__ bp2,
    const float* __restrict__ Wpr, const float* __restrict__ bpr,
    const float* __restrict__ Wh,  const float* __restrict__ bh,
    float* __restrict__ out)
{
    __shared__ __align__(16) float Wp1L[128 * 64];
    __shared__ __align__(16) float Wp2L[128 * 64];
    __shared__ __align__(16) float W2L[64 * 128];
    __shared__ __align__(16) float Wprs[64 * 20];
    __shared__ float Whs[40];
    __shared__ float bp1s[64], bp2s[64], b2s[128], bprs[20], bhs[2];
    __shared__ __align__(16) float z1r_[2][CCH][128];  // planar r|i
    __shared__ __align__(16) float x2r_[2][CCH][128];
    __shared__ __align__(16) float z2r_[2][CCH][128];
    __shared__ __align__(16) float h1b_[2][CCH][64];
    __shared__ __align__(16) float h2b_[2][CCH][64];
    __shared__ float h3b_[2][CCH][20];
    __shared__ __align__(16) float fbuf[2][CCH][128];  // W0 forcing staging

    const int tid = threadIdx.x, wid = tid >> 6, lane = tid & 63;
    const int b = blockIdx.x;
    const int* xb = xin + b * T_SEQ;

    // ---- stage weights/biases into LDS (rolled) ----
    for (int idx = tid; idx < 128 * 64; idx += 512) {
        Wp1L[idx] = Wp1[idx];
        Wp2L[idx] = Wp2[idx];
    }
    for (int idx = tid; idx < 64 * 128; idx += 512) {
        int k = idx >> 7, c = idx & 127;
        W2L[idx] = (c < 64) ? W2r[k * 64 + c] : W2i[k * 64 + (c - 64)];
    }
    for (int idx = tid; idx < 64 * 20; idx += 512) Wprs[idx] = Wpr[idx];
    if (tid < 64) { bp1s[tid] = bp1[tid]; bp2s[tid] = bp2[tid]; }
    if (tid < 128) b2s[tid] = (tid < 64) ? b2r[tid] : b2i[tid - 64];
    if (tid < 40) Whs[tid] = Wh[tid];
    if (tid < 20) bprs[tid] = bpr[tid];
    if (tid < 2)  bhs[tid]  = bh[tid];

    const float C1 = 1.0f + DT_C * MU_C;
    const float SD = DT_C * SC_C;
    v2f zH = { 0.1f, 0.0f };
    float domH = 0.f;
    if (wid == 0) domH = DT_C * om1[lane];
    if (wid == 1) domH = DT_C * om2[lane];

    if (wid == 0) {    // prologue: stage chunk-0 forcing into fbuf[0]
        const float* tl = tab + 2 * lane;
        v2f g0 = *(const v2f*)(tl + (size_t)xb[0] * 128);
        v2f g1 = *(const v2f*)(tl + (size_t)xb[1] * 128);
        v2f g2 = *(const v2f*)(tl + (size_t)xb[2] * 128);
        v2f g3 = *(const v2f*)(tl + (size_t)xb[3] * 128);
        v2f g4 = *(const v2f*)(tl + (size_t)xb[4] * 128);
        v2f g5 = *(const v2f*)(tl + (size_t)xb[5] * 128);
        v2f g6 = *(const v2f*)(tl + (size_t)xb[6] * 128);
        v2f g7 = *(const v2f*)(tl + (size_t)xb[7] * 128);
        fbuf[0][0][lane] = g0.x; fbuf[0][0][64 + lane] = g0.y;
        fbuf[0][1][lane] = g1.x; fbuf[0][1][64 + lane] = g1.y;
        fbuf[0][2][lane] = g2.x; fbuf[0][2][64 + lane] = g2.y;
        fbuf[0][3][lane] = g3.x; fbuf[0][3][64 + lane] = g3.y;
        fbuf[0][4][lane] = g4.x; fbuf[0][4][64 + lane] = g4.y;
        fbuf[0][5][lane] = g5.x; fbuf[0][5][64 + lane] = g5.y;
        fbuf[0][6][lane] = g6.x; fbuf[0][6][64 + lane] = g6.y;
        fbuf[0][7][lane] = g7.x; fbuf[0][7][64 + lane] = g7.y;
    }
    __syncthreads();

    for (int it = 0; it < NIT; ++it) {
        if (wid == 0) {                      // hopf1, chunk it
            const int c = it;
            if (c < NCH) {
                const int s = c & 1;
                const int cn = (c + 1 < NCH) ? (c + 1) : (NCH - 1);
                const int sn = cn & 1;
                // issue next-chunk gathers (8 named regs, stay in flight)
                const float* tl = tab + 2 * lane;
                const int* xc = xb + cn * 8;
                v2f g0 = *(const v2f*)(tl + (size_t)xc[0] * 128);
                v2f g1 = *(const v2f*)(tl + (size_t)xc[1] * 128);
                v2f g2 = *(const v2f*)(tl + (size_t)xc[2] * 128);
                v2f g3 = *(const v2f*)(tl + (size_t)xc[3] * 128);
                v2f g4 = *(const v2f*)(tl + (size_t)xc[4] * 128);
                v2f g5 = *(const v2f*)(tl + (size_t)xc[5] * 128);
                v2f g6 = *(const v2f*)(tl + (size_t)xc[6] * 128);
                v2f g7 = *(const v2f*)(tl + (size_t)xc[7] * 128);
                // compute chunk c (rolled over tokens)
                for (int j = 0; j < CCH; ++j) {
                    const float dcr = SD * fbuf[s][j][lane];
                    const float dci = SD * fbuf[s][j][64 + lane];
                    float zr = zH.x, zi = zH.y;
#pragma unroll 2
                    for (int st = 0; st < NSTEP; ++st) {
                        float wr = fmaf(-domH, zi, dcr);
                        float wi = fmaf( domH, zr, dci);
                        float r2 = fmaf(zr, zr, zi * zi);
                        float g  = fmaf(-DT_C, r2, C1);
                        zr = fmaf(g, zr, wr);
                        zi = fmaf(g, zi, wi);
                    }
                    zH.x = zr; zH.y = zi;
                    z1r_[s][j][lane]      = zr;
                    z1r_[s][j][64 + lane] = zi;
                }
                // store staged forcing for chunk cn
                fbuf[sn][0][lane] = g0.x; fbuf[sn][0][64 + lane] = g0.y;
                fbuf[sn][1][lane] = g1.x; fbuf[sn][1][64 + lane] = g1.y;
                fbuf[sn][2][lane] = g2.x; fbuf[sn][2][64 + lane] = g2.y;
                fbuf[sn][3][lane] = g3.x; fbuf[sn][3][64 + lane] = g3.y;
                fbuf[sn][4][lane] = g4.x; fbuf[sn][4][64 + lane] = g4.y;
                fbuf[sn][5][lane] = g5.x; fbuf[sn][5][64 + lane] = g5.y;
                fbuf[sn][6][lane] = g6.x; fbuf[sn][6][64 + lane] = g6.y;
                fbuf[sn][7][lane] = g7.x; fbuf[sn][7][64 + lane] = g7.y;
            }
        } else if (wid == 1) {               // hopf2, chunk it-3
            const int c = it - 3;
            if (0 <= c && c < NCH) {
                const int s = c & 1;
                for (int j = 0; j < CCH; ++j) {
                    const float dcr = SD * x2r_[s][j][lane];
                    const float dci = SD * x2r_[s][j][64 + lane];
                    float zr = zH.x, zi = zH.y;
#pragma unroll 2
                    for (int st = 0; st < NSTEP; ++st) {
                        float wr = fmaf(-domH, zi, dcr);
                        float wi = fmaf( domH, zr, dci);
                        float r2 = fmaf(zr, zr, zi * zi);
                        float g  = fmaf(-DT_C, r2, C1);
                        zr = fmaf(g, zr, wr);
                        zi = fmaf(g, zi, wi);
                    }
                    zH.x = zr; zH.y = zi;
                    z2r_[s][j][lane]      = zr;
                    z2r_[s][j][64 + lane] = zi;
                }
            }
        } else if (wid == 2) {               // h1 GEMM, chunk it-1
            const int c = it - 1;
            if (0 <= c && c < NCH) {
                const int s = c & 1;
                float acc[8] = {0,0,0,0,0,0,0,0};
#pragma unroll 2
                for (int kq = 0; kq < 32; ++kq) {
                    float w0 = Wp1L[(4*kq+0)*64 + lane];
                    float w1 = Wp1L[(4*kq+1)*64 + lane];
                    float w2 = Wp1L[(4*kq+2)*64 + lane];
                    float w3 = Wp1L[(4*kq+3)*64 + lane];
#pragma unroll
                    for (int r = 0; r < 8; ++r) {
                        float4 zv = *(const float4*)&z1r_[s][r][4*kq];
                        acc[r] = fmaf(zv.x, w0, acc[r]);
                        acc[r] = fmaf(zv.y, w1, acc[r]);
                        acc[r] = fmaf(zv.z, w2, acc[r]);
                        acc[r] = fmaf(zv.w, w3, acc[r]);
                    }
                }
#pragma unroll
                for (int r = 0; r < 8; ++r)
                    h1b_[s][r][lane] = fmaxf(acc[r] + bp1s[lane], 0.f);
            }
        } else if (wid == 3) {               // h2 GEMM, chunk it-4
            const int c = it - 4;
            if (0 <= c && c < NCH) {
                const int s = c & 1;
                float acc[8] = {0,0,0,0,0,0,0,0};
#pragma unroll 2
                for (int kq = 0; kq < 32; ++kq) {
                    float w0 = Wp2L[(4*kq+0)*64 + lane];
                    float w1 = Wp2L[(4*kq+1)*64 + lane];
                    float w2 = Wp2L[(4*kq+2)*64 + lane];
                    float w3 = Wp2L[(4*kq+3)*64 + lane];
#pragma unroll
                    for (int r = 0; r < 8; ++r) {
                        float4 zv = *(const float4*)&z2r_[s][r][4*kq];
                        acc[r] = fmaf(zv.x, w0, acc[r]);
                        acc[r] = fmaf(zv.y, w1, acc[r]);
                        acc[r] = fmaf(zv.z, w2, acc[r]);
                        acc[r] = fmaf(zv.w, w3, acc[r]);
                    }
                }
#pragma unroll
                for (int r = 0; r < 8; ++r)
                    h2b_[s][r][lane] = fmaxf(acc[r] + bp2s[lane], 0.f);
            }
        } else if (wid == 4 || wid == 5) {   // x2 GEMM, chunk it-2
            const int c = it - 2;
            if (0 <= c && c < NCH) {
                const int s = c & 1;
                const int rb = (wid - 4) * 4;
                float ar[4] = {0,0,0,0}, ai[4] = {0,0,0,0};
#pragma unroll 2
                for (int kq = 0; kq < 16; ++kq) {
                    float wr0 = W2L[(4*kq+0)*128 + lane];
                    float wi0 = W2L[(4*kq+0)*128 + 64 + lane];
                    float wr1 = W2L[(4*kq+1)*128 + lane];
                    float wi1 = W2L[(4*kq+1)*128 + 64 + lane];
                    float wr2 = W2L[(4*kq+2)*128 + lane];
                    float wi2 = W2L[(4*kq+2)*128 + 64 + lane];
                    float wr3 = W2L[(4*kq+3)*128 + lane];
                    float wi3 = W2L[(4*kq+3)*128 + 64 + lane];
#pragma unroll
                    for (int r = 0; r < 4; ++r) {
                        float4 hv = *(const float4*)&h1b_[s][rb + r][4*kq];
                        ar[r] = fmaf(hv.x, wr0, ar[r]);
                        ai[r] = fmaf(hv.x, wi0, ai[r]);
                        ar[r] = fmaf(hv.y, wr1, ar[r]);
                        ai[r] = fmaf(hv.y, wi1, ai[r]);
                        ar[r] = fmaf(hv.z, wr2, ar[r]);
                        ai[r] = fmaf(hv.z, wi2, ai[r]);
                        ar[r] = fmaf(hv.w, wr3, ar[r]);
                        ai[r] = fmaf(hv.w, wi3, ai[r]);
                    }
                }
#pragma unroll
                for (int r = 0; r < 4; ++r) {
                    x2r_[s][rb + r][lane]      = fmaxf(ar[r] + b2s[lane], 0.f);
                    x2r_[s][rb + r][64 + lane] = fmaxf(ai[r] + b2s[64 + lane], 0.f);
                }
            }
        } else {                             // W6/W7: h3 tanh, chunk it-5
            const int c = it - 5;
            if (0 <= c && c < NCH && lane < 40) {
                const int s = c & 1;
                const int rb = (wid - 6) * 4;
                const int rr = lane / 20, j = lane % 20;
                const int r0 = rb + rr, r1 = rb + rr + 2;
                float a0 = 0.f, a1 = 0.f;
#pragma unroll 4
                for (int k = 0; k < 64; ++k) {
                    float w = Wprs[k * 20 + j];
                    a0 = fmaf(h2b_[s][r0][k], w, a0);
                    a1 = fmaf(h2b_[s][r1][k], w, a1);
                }
                h3b_[s][r0][j] = tanhf(a0 + bprs[j]);
                h3b_[s][r1][j] = tanhf(a1 + bprs[j]);
            }
            if (wid == 6) {                  // logits, chunk it-6
                const int co = it - 6;
                if (0 <= co && co < NCH && lane < 16) {
                    const int s = co & 1;
                    const int r = lane >> 1, cc = lane & 1;
                    float a = bhs[cc];
#pragma unroll 4
                    for (int p = 0; p < 20; ++p)
                        a = fmaf(h3b_[s][r][p], Whs[p * 2 + cc], a);
                    const int t = co * CCH + r;
                    out[(size_t)b * (T_SEQ * 2) + t * 2 + cc] = a;
                }
            }
        }
        __syncthreads();
    }
}

// ---------------------------------------------------------------------------
extern "C" void kernel_launch(void* const* d_in, const int* in_sizes, int n_in,
                              void* d_out, int out_size, void* d_ws, size_t ws_size,
                              hipStream_t stream) {
    const int*   x   = (const int*)  d_in[0];
    const float* E   = (const float*)d_in[1];
    const float* W1r = (const float*)d_in[2];
    const float* b1r = (const float*)d_in[3];
    const float* W1i = (const float*)d_in[4];
    const float* b1i = (const float*)d_in[5];
    const float* om1 = (const float*)d_in[6];
    const float* Wp1 = (const float*)d_in[7];
    const float* bp1 = (const float*)d_in[8];
    const float* W2r = (const float*)d_in[9];
    const float* b2r = (const float*)d_in[10];
    const float* W2i = (const float*)d_in[11];
    const float* b2i = (const float*)d_in[12];
    const float* om2 = (const float*)d_in[13];
    const float* Wp2 = (const float*)d_in[14];
    const float* bp2 = (const float*)d_in[15];
    const float* Wpr = (const float*)d_in[16];
    const float* bpr = (const float*)d_in[17];
    const float* Wh  = (const float*)d_in[18];
    const float* bh  = (const float*)d_in[19];

    float* tab = (float*)d_ws;   // relu(E@W1cat+b1cat), [32000][128] — 16.4 MB

    k0_table<<<NVOC / 128, 256, 0, stream>>>(E, W1r, b1r, W1i, b1i, tab);
    donn_pipe<<<B_BAT, 512, 0, stream>>>(tab, x, om1, om2,
                                         Wp1, bp1, W2r, b2r, W2i, b2i,
                                         Wp2, bp2, Wpr, bpr, Wh, bh,
                                         (float*)d_out);
}

// Round 9
// 243.912 us; speedup vs baseline: 1.5360x; 1.5360x over previous
//
#include <hip/hip_runtime.h>

#define T_SEQ 512
#define B_BAT 256
#define ED_ 100
#define NVOC 32000
#define DT_C 1e-3f
#define SC_C 0.2f
#define MU_C 1.0f
#define NSTEP 20
#define CCH 8                 // tokens per pipeline chunk
#define NCH (T_SEQ / CCH)     // 64 chunks
#define NIT (NCH + 6)         // pipeline depth 7 stages

typedef float v2f __attribute__((ext_vector_type(2)));
typedef float v4f __attribute__((ext_vector_type(4)));

// packed FMA, scalar splat from LO half of pair sv:  acc.{x,y} += sv.x * w.{x,y}
#define PK_FMA_LO(acc, sv, w)                                                  \
    asm("v_pk_fma_f32 %0, %1, %2, %0 op_sel:[0,0,0] op_sel_hi:[0,1,1]"         \
        : "+v"(acc) : "v"(sv), "v"(w))
// packed FMA, scalar splat from HI half of pair sv:  acc.{x,y} += sv.y * w.{x,y}
#define PK_FMA_HI(acc, sv, w)                                                  \
    asm("v_pk_fma_f32 %0, %1, %2, %0 op_sel:[1,0,0] op_sel_hi:[1,1,1]"         \
        : "+v"(acc) : "v"(sv), "v"(w))

__device__ __forceinline__ float fast_tanh(float x) {
    float e = __expf(2.f * x);
    return 1.f - 2.f * __builtin_amdgcn_rcpf(e + 1.f);
}

// ---------------------------------------------------------------------------
// K0: tab[v][c] = relu(E[v] @ W1cat + b1cat), c interleaved (2u+p). 250 blocks.
// ---------------------------------------------------------------------------
__global__ __launch_bounds__(256) void k0_table(
    const float* __restrict__ E,
    const float* __restrict__ W1r, const float* __restrict__ b1r,
    const float* __restrict__ W1i, const float* __restrict__ b1i,
    float* __restrict__ tab)
{
    __shared__ float embT[128 * 104];
    __shared__ float Wc[100 * 128];
    __shared__ float bias[128];
    const int tid = threadIdx.x;
    const int row0g = blockIdx.x * 128;

    for (int idx = tid; idx < 100 * 128; idx += 256) {
        int k = idx >> 7, c = idx & 127;
        Wc[idx] = (c & 1) ? W1i[k * 64 + (c >> 1)] : W1r[k * 64 + (c >> 1)];
    }
    if (tid < 128) bias[tid] = (tid & 1) ? b1i[tid >> 1] : b1r[tid >> 1];
    {
        int r = tid >> 1, half = tid & 1;
        const float4* src = (const float4*)(E + (size_t)(row0g + r) * ED_);
        float4* dst = (float4*)&embT[r * 104];
        for (int j = half; j < 25; j += 2) dst[j] = src[j];
    }
    __syncthreads();

    const int col0 = (tid & 15) * 8;
    const int row0 = (tid >> 4) * 8;
    float acc[8][8];
#pragma unroll
    for (int i = 0; i < 8; ++i)
#pragma unroll
        for (int j = 0; j < 8; ++j) acc[i][j] = 0.f;

    for (int k0 = 0; k0 < 100; k0 += 4) {
        float ev[8][4];
#pragma unroll
        for (int i = 0; i < 8; ++i)
            *(float4*)ev[i] = *(const float4*)&embT[(row0 + i) * 104 + k0];
#pragma unroll
        for (int kk = 0; kk < 4; ++kk) {
            float4 wA = *(const float4*)&Wc[(k0 + kk) * 128 + col0];
            float4 wB = *(const float4*)&Wc[(k0 + kk) * 128 + col0 + 4];
#pragma unroll
            for (int i = 0; i < 8; ++i) {
                float e = ev[i][kk];
                acc[i][0] = fmaf(e, wA.x, acc[i][0]);
                acc[i][1] = fmaf(e, wA.y, acc[i][1]);
                acc[i][2] = fmaf(e, wA.z, acc[i][2]);
                acc[i][3] = fmaf(e, wA.w, acc[i][3]);
                acc[i][4] = fmaf(e, wB.x, acc[i][4]);
                acc[i][5] = fmaf(e, wB.y, acc[i][5]);
                acc[i][6] = fmaf(e, wB.z, acc[i][6]);
                acc[i][7] = fmaf(e, wB.w, acc[i][7]);
            }
        }
    }
#pragma unroll
    for (int i = 0; i < 8; ++i) {
        float4 o0, o1;
        o0.x = fmaxf(acc[i][0] + bias[col0 + 0], 0.f);
        o0.y = fmaxf(acc[i][1] + bias[col0 + 1], 0.f);
        o0.z = fmaxf(acc[i][2] + bias[col0 + 2], 0.f);
        o0.w = fmaxf(acc[i][3] + bias[col0 + 3], 0.f);
        o1.x = fmaxf(acc[i][4] + bias[col0 + 4], 0.f);
        o1.y = fmaxf(acc[i][5] + bias[col0 + 5], 0.f);
        o1.z = fmaxf(acc[i][6] + bias[col0 + 6], 0.f);
        o1.w = fmaxf(acc[i][7] + bias[col0 + 7], 0.f);
        size_t base = (size_t)(row0g + row0 + i) * 128 + col0;
        *(float4*)&tab[base] = o0;
        *(float4*)&tab[base + 4] = o1;
    }
}

// ---------------------------------------------------------------------------
// Fused pipeline, one block per batch element, 8 waves, 7-stage chunk
// pipeline. All rings interleaved (r,i) pairs; GEMMs use col-pair pk_fma with
// paired v2f weights (LDS-instruction diet, packed VALU).
// ---------------------------------------------------------------------------
__global__ __launch_bounds__(512, 1) void donn_pipe(
    const float* __restrict__ tab, const int* __restrict__ xin,
    const float* __restrict__ om1, const float* __restrict__ om2,
    const float* __restrict__ Wp1, const float* __restrict__ bp1,
    const float* __restrict__ W2r, const float* __restrict__ b2r,
    const float* __restrict__ W2i, const float* __restrict__ b2i,
    const float* __restrict__ Wp2, const float* __restrict__ bp2,
    const float* __restrict__ Wpr, const float* __restrict__ bpr,
    const float* __restrict__ Wh,  const float* __restrict__ bh,
    float* __restrict__ out)
{
    __shared__ __align__(16) v2f   Wp1P[128 * 32];   // [kI][cp] col-pairs
    __shared__ __align__(16) v2f   Wp2P[128 * 32];
    __shared__ __align__(16) v2f   W2P[64 * 64];     // [k][u] (r,i) pairs
    __shared__ __align__(16) float WprT[20 * 68];    // [j][k] padded
    __shared__ float Whs[40];
    __shared__ v2f   bp1P[32], bp2P[32], b2P[64];
    __shared__ float bprs[20], bhs[2];
    __shared__ __align__(16) float z1r_[2][CCH][128];  // interleaved kI = 2u+p
    __shared__ __align__(16) float x2r_[2][CCH][128];
    __shared__ __align__(16) float z2r_[2][CCH][128];
    __shared__ __align__(16) float h1b_[2][CCH][64];
    __shared__ __align__(16) float h2b_[2][CCH][64];
    __shared__ float h3b_[2][CCH][20];
    __shared__ __align__(16) float fbuf[2][CCH][128];  // interleaved forcing

    const int tid = threadIdx.x, wid = tid >> 6, lane = tid & 63;
    const int b = blockIdx.x;
    const int* xb = xin + b * T_SEQ;

    // ---- stage weights/biases into LDS ----
    for (int idx = tid; idx < 128 * 32; idx += 512) {
        int kI = idx >> 5, cp = idx & 31;
        int kR = (kI & 1) * 64 + (kI >> 1);
        Wp1P[idx] = (v2f){ Wp1[kR * 64 + 2 * cp], Wp1[kR * 64 + 2 * cp + 1] };
        Wp2P[idx] = (v2f){ Wp2[kR * 64 + 2 * cp], Wp2[kR * 64 + 2 * cp + 1] };
    }
    for (int idx = tid; idx < 64 * 64; idx += 512) {
        int k = idx >> 6, u = idx & 63;
        W2P[idx] = (v2f){ W2r[k * 64 + u], W2i[k * 64 + u] };
    }
    for (int idx = tid; idx < 20 * 68; idx += 512) {
        int j = idx / 68, k = idx % 68;
        WprT[idx] = (k < 64) ? Wpr[k * 20 + j] : 0.f;
    }
    if (tid < 32) { bp1P[tid] = (v2f){ bp1[2*tid], bp1[2*tid+1] };
                    bp2P[tid] = (v2f){ bp2[2*tid], bp2[2*tid+1] }; }
    if (tid < 64) b2P[tid] = (v2f){ b2r[tid], b2i[tid] };
    if (tid < 40) Whs[tid] = Wh[tid];
    if (tid < 20) bprs[tid] = bpr[tid];
    if (tid < 2)  bhs[tid]  = bh[tid];

    const float C1 = 1.0f + DT_C * MU_C;
    const float SD = DT_C * SC_C;
    v2f zH = { 0.1f, 0.0f };
    float domH = 0.f;
    if (wid == 0) domH = DT_C * om1[lane];
    if (wid == 1) domH = DT_C * om2[lane];

    if (wid == 0) {    // prologue: stage chunk-0 forcing
        const float* tl = tab + 2 * lane;
        v2f g0 = *(const v2f*)(tl + (size_t)xb[0] * 128);
        v2f g1 = *(const v2f*)(tl + (size_t)xb[1] * 128);
        v2f g2 = *(const v2f*)(tl + (size_t)xb[2] * 128);
        v2f g3 = *(const v2f*)(tl + (size_t)xb[3] * 128);
        v2f g4 = *(const v2f*)(tl + (size_t)xb[4] * 128);
        v2f g5 = *(const v2f*)(tl + (size_t)xb[5] * 128);
        v2f g6 = *(const v2f*)(tl + (size_t)xb[6] * 128);
        v2f g7 = *(const v2f*)(tl + (size_t)xb[7] * 128);
        *(v2f*)&fbuf[0][0][2*lane] = g0; *(v2f*)&fbuf[0][1][2*lane] = g1;
        *(v2f*)&fbuf[0][2][2*lane] = g2; *(v2f*)&fbuf[0][3][2*lane] = g3;
        *(v2f*)&fbuf[0][4][2*lane] = g4; *(v2f*)&fbuf[0][5][2*lane] = g5;
        *(v2f*)&fbuf[0][6][2*lane] = g6; *(v2f*)&fbuf[0][7][2*lane] = g7;
    }
    __syncthreads();

    for (int it = 0; it < NIT; ++it) {
        if (wid == 0) {                      // hopf1, chunk it
            const int c = it;
            if (c < NCH) {
                const int s = c & 1;
                const int cn = (c + 1 < NCH) ? (c + 1) : (NCH - 1);
                const int sn = cn & 1;
                const float* tl = tab + 2 * lane;
                const int* xc = xb + cn * 8;
                v2f g0 = *(const v2f*)(tl + (size_t)xc[0] * 128);
                v2f g1 = *(const v2f*)(tl + (size_t)xc[1] * 128);
                v2f g2 = *(const v2f*)(tl + (size_t)xc[2] * 128);
                v2f g3 = *(const v2f*)(tl + (size_t)xc[3] * 128);
                v2f g4 = *(const v2f*)(tl + (size_t)xc[4] * 128);
                v2f g5 = *(const v2f*)(tl + (size_t)xc[5] * 128);
                v2f g6 = *(const v2f*)(tl + (size_t)xc[6] * 128);
                v2f g7 = *(const v2f*)(tl + (size_t)xc[7] * 128);
                for (int j = 0; j < CCH; ++j) {
                    v2f f = *(const v2f*)&fbuf[s][j][2*lane];
                    const float dcr = SD * f.x, dci = SD * f.y;
                    float zr = zH.x, zi = zH.y;
#pragma unroll 2
                    for (int st = 0; st < NSTEP; ++st) {
                        float wr = fmaf(-domH, zi, dcr);
                        float wi = fmaf( domH, zr, dci);
                        float r2 = fmaf(zr, zr, zi * zi);
                        float g  = fmaf(-DT_C, r2, C1);
                        zr = fmaf(g, zr, wr);
                        zi = fmaf(g, zi, wi);
                    }
                    zH.x = zr; zH.y = zi;
                    *(v2f*)&z1r_[s][j][2*lane] = zH;
                }
                *(v2f*)&fbuf[sn][0][2*lane] = g0;
                *(v2f*)&fbuf[sn][1][2*lane] = g1;
                *(v2f*)&fbuf[sn][2][2*lane] = g2;
                *(v2f*)&fbuf[sn][3][2*lane] = g3;
                *(v2f*)&fbuf[sn][4][2*lane] = g4;
                *(v2f*)&fbuf[sn][5][2*lane] = g5;
                *(v2f*)&fbuf[sn][6][2*lane] = g6;
                *(v2f*)&fbuf[sn][7][2*lane] = g7;
            }
        } else if (wid == 1) {               // hopf2, chunk it-3
            const int c = it - 3;
            if (0 <= c && c < NCH) {
                const int s = c & 1;
                for (int j = 0; j < CCH; ++j) {
                    v2f f = *(const v2f*)&x2r_[s][j][2*lane];
                    const float dcr = SD * f.x, dci = SD * f.y;
                    float zr = zH.x, zi = zH.y;
#pragma unroll 2
                    for (int st = 0; st < NSTEP; ++st) {
                        float wr = fmaf(-domH, zi, dcr);
                        float wi = fmaf( domH, zr, dci);
                        float r2 = fmaf(zr, zr, zi * zi);
                        float g  = fmaf(-DT_C, r2, C1);
                        zr = fmaf(g, zr, wr);
                        zi = fmaf(g, zi, wi);
                    }
                    zH.x = zr; zH.y = zi;
                    *(v2f*)&z2r_[s][j][2*lane] = zH;
                }
            }
        } else if (wid == 2) {               // h1 GEMM, chunk it-1 (pk col-pair)
            const int c = it - 1;
            if (0 <= c && c < NCH) {
                const int s = c & 1;
                const int rg = lane >> 5, cp = lane & 31, r0 = rg * 4;
                v2f a0 = {0,0}, a1 = {0,0}, a2 = {0,0}, a3 = {0,0};
#pragma unroll 4
                for (int kq = 0; kq < 32; ++kq) {
                    v4f zv0 = *(const v4f*)&z1r_[s][r0+0][4*kq];
                    v4f zv1 = *(const v4f*)&z1r_[s][r0+1][4*kq];
                    v4f zv2 = *(const v4f*)&z1r_[s][r0+2][4*kq];
                    v4f zv3 = *(const v4f*)&z1r_[s][r0+3][4*kq];
                    v2f w0 = Wp1P[(4*kq+0)*32 + cp];
                    v2f w1 = Wp1P[(4*kq+1)*32 + cp];
                    v2f w2 = Wp1P[(4*kq+2)*32 + cp];
                    v2f w3 = Wp1P[(4*kq+3)*32 + cp];
                    PK_FMA_LO(a0, zv0.xy, w0); PK_FMA_HI(a0, zv0.xy, w1);
                    PK_FMA_LO(a0, zv0.zw, w2); PK_FMA_HI(a0, zv0.zw, w3);
                    PK_FMA_LO(a1, zv1.xy, w0); PK_FMA_HI(a1, zv1.xy, w1);
                    PK_FMA_LO(a1, zv1.zw, w2); PK_FMA_HI(a1, zv1.zw, w3);
                    PK_FMA_LO(a2, zv2.xy, w0); PK_FMA_HI(a2, zv2.xy, w1);
                    PK_FMA_LO(a2, zv2.zw, w2); PK_FMA_HI(a2, zv2.zw, w3);
                    PK_FMA_LO(a3, zv3.xy, w0); PK_FMA_HI(a3, zv3.xy, w1);
                    PK_FMA_LO(a3, zv3.zw, w2); PK_FMA_HI(a3, zv3.zw, w3);
                }
                v2f bb = bp1P[cp];
                v2f o0 = { fmaxf(a0.x + bb.x, 0.f), fmaxf(a0.y + bb.y, 0.f) };
                v2f o1 = { fmaxf(a1.x + bb.x, 0.f), fmaxf(a1.y + bb.y, 0.f) };
                v2f o2 = { fmaxf(a2.x + bb.x, 0.f), fmaxf(a2.y + bb.y, 0.f) };
                v2f o3 = { fmaxf(a3.x + bb.x, 0.f), fmaxf(a3.y + bb.y, 0.f) };
                *(v2f*)&h1b_[s][r0+0][2*cp] = o0;
                *(v2f*)&h1b_[s][r0+1][2*cp] = o1;
                *(v2f*)&h1b_[s][r0+2][2*cp] = o2;
                *(v2f*)&h1b_[s][r0+3][2*cp] = o3;
            }
        } else if (wid == 3) {               // h2 GEMM, chunk it-4 (pk col-pair)
            const int c = it - 4;
            if (0 <= c && c < NCH) {
                const int s = c & 1;
                const int rg = lane >> 5, cp = lane & 31, r0 = rg * 4;
                v2f a0 = {0,0}, a1 = {0,0}, a2 = {0,0}, a3 = {0,0};
#pragma unroll 4
                for (int kq = 0; kq < 32; ++kq) {
                    v4f zv0 = *(const v4f*)&z2r_[s][r0+0][4*kq];
                    v4f zv1 = *(const v4f*)&z2r_[s][r0+1][4*kq];
                    v4f zv2 = *(const v4f*)&z2r_[s][r0+2][4*kq];
                    v4f zv3 = *(const v4f*)&z2r_[s][r0+3][4*kq];
                    v2f w0 = Wp2P[(4*kq+0)*32 + cp];
                    v2f w1 = Wp2P[(4*kq+1)*32 + cp];
                    v2f w2 = Wp2P[(4*kq+2)*32 + cp];
                    v2f w3 = Wp2P[(4*kq+3)*32 + cp];
                    PK_FMA_LO(a0, zv0.xy, w0); PK_FMA_HI(a0, zv0.xy, w1);
                    PK_FMA_LO(a0, zv0.zw, w2); PK_FMA_HI(a0, zv0.zw, w3);
                    PK_FMA_LO(a1, zv1.xy, w0); PK_FMA_HI(a1, zv1.xy, w1);
                    PK_FMA_LO(a1, zv1.zw, w2); PK_FMA_HI(a1, zv1.zw, w3);
                    PK_FMA_LO(a2, zv2.xy, w0); PK_FMA_HI(a2, zv2.xy, w1);
                    PK_FMA_LO(a2, zv2.zw, w2); PK_FMA_HI(a2, zv2.zw, w3);
                    PK_FMA_LO(a3, zv3.xy, w0); PK_FMA_HI(a3, zv3.xy, w1);
                    PK_FMA_LO(a3, zv3.zw, w2); PK_FMA_HI(a3, zv3.zw, w3);
                }
                v2f bb = bp2P[cp];
                v2f o0 = { fmaxf(a0.x + bb.x, 0.f), fmaxf(a0.y + bb.y, 0.f) };
                v2f o1 = { fmaxf(a1.x + bb.x, 0.f), fmaxf(a1.y + bb.y, 0.f) };
                v2f o2 = { fmaxf(a2.x + bb.x, 0.f), fmaxf(a2.y + bb.y, 0.f) };
                v2f o3 = { fmaxf(a3.x + bb.x, 0.f), fmaxf(a3.y + bb.y, 0.f) };
                *(v2f*)&h2b_[s][r0+0][2*cp] = o0;
                *(v2f*)&h2b_[s][r0+1][2*cp] = o1;
                *(v2f*)&h2b_[s][r0+2][2*cp] = o2;
                *(v2f*)&h2b_[s][r0+3][2*cp] = o3;
            }
        } else if (wid == 4 || wid == 5) {   // x2 GEMM, chunk it-2 (pk pairs)
            const int c = it - 2;
            if (0 <= c && c < NCH) {
                const int s = c & 1;
                const int rb = (wid - 4) * 4;
                const int u = lane;
                v2f a0 = {0,0}, a1 = {0,0}, a2 = {0,0}, a3 = {0,0};
#pragma unroll 4
                for (int kq = 0; kq < 16; ++kq) {
                    v4f h0 = *(const v4f*)&h1b_[s][rb+0][4*kq];
                    v4f h1v = *(const v4f*)&h1b_[s][rb+1][4*kq];
                    v4f h2v = *(const v4f*)&h1b_[s][rb+2][4*kq];
                    v4f h3v = *(const v4f*)&h1b_[s][rb+3][4*kq];
                    v2f w0 = W2P[(4*kq+0)*64 + u];
                    v2f w1 = W2P[(4*kq+1)*64 + u];
                    v2f w2 = W2P[(4*kq+2)*64 + u];
                    v2f w3 = W2P[(4*kq+3)*64 + u];
                    PK_FMA_LO(a0, h0.xy, w0);  PK_FMA_HI(a0, h0.xy, w1);
                    PK_FMA_LO(a0, h0.zw, w2);  PK_FMA_HI(a0, h0.zw, w3);
                    PK_FMA_LO(a1, h1v.xy, w0); PK_FMA_HI(a1, h1v.xy, w1);
                    PK_FMA_LO(a1, h1v.zw, w2); PK_FMA_HI(a1, h1v.zw, w3);
                    PK_FMA_LO(a2, h2v.xy, w0); PK_FMA_HI(a2, h2v.xy, w1);
                    PK_FMA_LO(a2, h2v.zw, w2); PK_FMA_HI(a2, h2v.zw, w3);
                    PK_FMA_LO(a3, h3v.xy, w0); PK_FMA_HI(a3, h3v.xy, w1);
                    PK_FMA_LO(a3, h3v.zw, w2); PK_FMA_HI(a3, h3v.zw, w3);
                }
                v2f bb = b2P[u];
                v2f o0 = { fmaxf(a0.x + bb.x, 0.f), fmaxf(a0.y + bb.y, 0.f) };
                v2f o1 = { fmaxf(a1.x + bb.x, 0.f), fmaxf(a1.y + bb.y, 0.f) };
                v2f o2 = { fmaxf(a2.x + bb.x, 0.f), fmaxf(a2.y + bb.y, 0.f) };
                v2f o3 = { fmaxf(a3.x + bb.x, 0.f), fmaxf(a3.y + bb.y, 0.f) };
                *(v2f*)&x2r_[s][rb+0][2*u] = o0;
                *(v2f*)&x2r_[s][rb+1][2*u] = o1;
                *(v2f*)&x2r_[s][rb+2][2*u] = o2;
                *(v2f*)&x2r_[s][rb+3][2*u] = o3;
            }
        } else {                             // W6/W7: h3 tanh, chunk it-5
            const int c = it - 5;
            if (0 <= c && c < NCH && lane < 40) {
                const int s = c & 1;
                const int rb = (wid - 6) * 4;
                const int rr = lane / 20, j = lane % 20;
                const int r0 = rb + rr, r1 = rb + rr + 2;
                float a0 = 0.f, a1 = 0.f;
#pragma unroll 4
                for (int kq = 0; kq < 16; ++kq) {
                    float4 w  = *(const float4*)&WprT[j * 68 + 4*kq];
                    float4 hA = *(const float4*)&h2b_[s][r0][4*kq];
                    float4 hB = *(const float4*)&h2b_[s][r1][4*kq];
                    a0 = fmaf(hA.x, w.x, a0); a0 = fmaf(hA.y, w.y, a0);
                    a0 = fmaf(hA.z, w.z, a0); a0 = fmaf(hA.w, w.w, a0);
                    a1 = fmaf(hB.x, w.x, a1); a1 = fmaf(hB.y, w.y, a1);
                    a1 = fmaf(hB.z, w.z, a1); a1 = fmaf(hB.w, w.w, a1);
                }
                h3b_[s][r0][j] = fast_tanh(a0 + bprs[j]);
                h3b_[s][r1][j] = fast_tanh(a1 + bprs[j]);
            }
            if (wid == 6) {                  // logits, chunk it-6
                const int co = it - 6;
                if (0 <= co && co < NCH && lane < 16) {
                    const int s = co & 1;
                    const int r = lane >> 1, cc = lane & 1;
                    float a = bhs[cc];
#pragma unroll 4
                    for (int p = 0; p < 20; ++p)
                        a = fmaf(h3b_[s][r][p], Whs[p * 2 + cc], a);
                    const int t = co * CCH + r;
                    out[(size_t)b * (T_SEQ * 2) + t * 2 + cc] = a;
                }
            }
        }
        __syncthreads();
    }
}

// ---------------------------------------------------------------------------
extern "C" void kernel_launch(void* const* d_in, const int* in_sizes, int n_in,
                              void* d_out, int out_size, void* d_ws, size_t ws_size,
                              hipStream_t stream) {
    const int*   x   = (const int*)  d_in[0];
    const float* E   = (const float*)d_in[1];
    const float* W1r = (const float*)d_in[2];
    const float* b1r = (const float*)d_in[3];
    const float* W1i = (const float*)d_in[4];
    const float* b1i = (const float*)d_in[5];
    const float* om1 = (const float*)d_in[6];
    const float* Wp1 = (const float*)d_in[7];
    const float* bp1 = (const float*)d_in[8];
    const float* W2r = (const float*)d_in[9];
    const float* b2r = (const float*)d_in[10];
    const float* W2i = (const float*)d_in[11];
    const float* b2i = (const float*)d_in[12];
    const float* om2 = (const float*)d_in[13];
    const float* Wp2 = (const float*)d_in[14];
    const float* bp2 = (const float*)d_in[15];
    const float* Wpr = (const float*)d_in[16];
    const float* bpr = (const float*)d_in[17];
    const float* Wh  = (const float*)d_in[18];
    const float* bh  = (const float*)d_in[19];

    float* tab = (float*)d_ws;   // relu(E@W1cat+b1cat), [32000][128] — 16.4 MB

    k0_table<<<NVOC / 128, 256, 0, stream>>>(E, W1r, b1r, W1i, b1i, tab);
    donn_pipe<<<B_BAT, 512, 0, stream>>>(tab, x, om1, om2,
                                         Wp1, bp1, W2r, b2r, W2i, b2i,
                                         Wp2, bp2, Wpr, bpr, Wh, bh,
                                         (float*)d_out);
}